// Round 9
// baseline (222.351 us; speedup 1.0000x reference)
//
#include <hip/hip_runtime.h>
#include <hip/hip_bf16.h>

// B=4, S=2048, TEXT_DIM=768, VISION_DIM=768, HIDDEN=512, HEADS=8, HEAD_DIM=64
#define BATCH 4
#define SEQ 2048
#define TDIM 768
#define VDIM 768
#define HID 512
#define NHEADS 8
#define HDIM 64
#define MROWS (BATCH * SEQ)   // 8192
#define NQKV (3 * HID)        // 1536

typedef unsigned short ushort_t;
typedef __attribute__((ext_vector_type(8))) short short8;
typedef __attribute__((ext_vector_type(4))) short short4v;
typedef __attribute__((ext_vector_type(4))) float floatx4;
typedef __attribute__((ext_vector_type(4))) unsigned int uint4v;

// 0.125 * log2(e): folded into Q so softmax uses exp2
#define QSCALE 0.18033688011112042f

__device__ __forceinline__ ushort_t bf16_rne(float f) {
    unsigned int u = __float_as_uint(f);
    u = (u + 0x7fffu + ((u >> 16) & 1u)) >> 16;
    return (ushort_t)u;
}

__device__ __forceinline__ float bf16_to_f(ushort_t v) {
    return __uint_as_float(((unsigned)v) << 16);
}

__device__ __forceinline__ void async16(const ushort_t* g, ushort_t* l) {
    __builtin_amdgcn_global_load_lds(
        (const __attribute__((address_space(1))) unsigned int*)g,
        (__attribute__((address_space(3))) unsigned int*)l, 16, 0, 0);
}

// ---------------------------------------------------------------------------
// Prep kernel: conv_x (blocks 0..6143) + weight transposes (blocks 6144..8447).
// conv: X fp32 -> bf16.  transp: Wq/Wk/Wv -> Wqkvt [1536][768]; Wo -> Wot [768][512].
// ---------------------------------------------------------------------------
__global__ __launch_bounds__(256) void prep(
    const float* __restrict__ X, ushort_t* __restrict__ Xb,
    const float* __restrict__ Wq, const float* __restrict__ Wk,
    const float* __restrict__ Wv, const float* __restrict__ Wo,
    ushort_t* __restrict__ Wqkvt, ushort_t* __restrict__ Wot)
{
    __shared__ float tile[32][33];
    const int bx = blockIdx.x;
    if (bx < 6144) {
        const int i = (bx * 256 + threadIdx.x) * 4;
        const floatx4 v = *(const floatx4*)(X + i);
        short4v o;
#pragma unroll
        for (int j = 0; j < 4; ++j) o[j] = (short)bf16_rne(v[j]);
        *(short4v*)(Xb + i) = o;
        return;
    }
    const int t = bx - 6144;        // 0..2303
    const int z = t / 576;          // 0..3
    const int rem = t % 576;
    const int bxx = rem % 24;
    const int byy = rem / 24;

    const float* src;
    ushort_t* dst;
    int R, C;
    if (z < 3) {
        src = (z == 0) ? Wq : (z == 1) ? Wk : Wv;
        dst = Wqkvt + (size_t)z * HID * TDIM;
        R = TDIM; C = HID;
    } else {
        src = Wo; dst = Wot; R = HID; C = VDIM;
    }
    const int tx = threadIdx.x & 31, ty = threadIdx.x >> 5;  // 32 x 8
    const int c0 = bxx * 32, r0 = byy * 32;
    if (c0 >= C || r0 >= R) return;
#pragma unroll
    for (int i = 0; i < 4; ++i)
        tile[ty + i * 8][tx] = src[(size_t)(r0 + ty + i * 8) * C + c0 + tx];
    __syncthreads();
#pragma unroll
    for (int i = 0; i < 4; ++i)
        dst[(size_t)(c0 + ty + i * 8) * R + r0 + tx] = bf16_rne(tile[tx][ty + i * 8]);
}

// ---------------------------------------------------------------------------
// m97-style bf16 MFMA GEMM mainloop: C(128x128) = A[M][K] x Bt[N][K]^T.
// ---------------------------------------------------------------------------
template<int KD, bool SWAPPED>
__device__ __forceinline__ void gemm128(
    const ushort_t* __restrict__ A, const ushort_t* __restrict__ Bt,
    int m0, int n0, ushort_t* As, ushort_t* Bs, floatx4 (&acc)[4][4])
{
    const int tid  = threadIdx.x;
    const int lane = tid & 63;
    const int w    = tid >> 6;
    const int l15  = lane & 15;
    const int quad = lane >> 4;
    const int wrow = w >> 1;
    const int wcol = w & 1;

    const int srow = lane >> 3;        // 0..7
    const int scol = (lane & 7) * 8;   // k elem offset

    const ushort_t* ga = A  + (size_t)(m0 + w * 32 + srow) * KD + scol;
    const ushort_t* gb = Bt + (size_t)(n0 + w * 32 + srow) * KD + scol;
    ushort_t* la = As + (w * 32) * 64;
    ushort_t* lb = Bs + (w * 32) * 64;

    for (int kt = 0; kt < KD; kt += 64) {
#pragma unroll
        for (int i = 0; i < 4; ++i) {
            async16(ga + (size_t)(i * 8) * KD + kt, la + i * 8 * 64);
            async16(gb + (size_t)(i * 8) * KD + kt, lb + i * 8 * 64);
        }
        __syncthreads();
#pragma unroll
        for (int half = 0; half < 2; ++half) {
            const int kk = half * 32 + quad * 8;
            short8 af[4], bf[4];
#pragma unroll
            for (int t = 0; t < 4; ++t) {
                af[t] = *(const short8*)&As[(wrow * 64 + t * 16 + l15) * 64 + kk];
                bf[t] = *(const short8*)&Bs[(wcol * 64 + t * 16 + l15) * 64 + kk];
            }
#pragma unroll
            for (int mi = 0; mi < 4; ++mi)
#pragma unroll
                for (int ni = 0; ni < 4; ++ni) {
                    if (SWAPPED)
                        acc[mi][ni] = __builtin_amdgcn_mfma_f32_16x16x32_bf16(
                            bf[ni], af[mi], acc[mi][ni], 0, 0, 0);
                    else
                        acc[mi][ni] = __builtin_amdgcn_mfma_f32_16x16x32_bf16(
                            af[mi], bf[ni], acc[mi][ni], 0, 0, 0);
                }
        }
        __syncthreads();
    }
}

// ---------------------------------------------------------------------------
// Kernel 1: QKV projection, bf16 MFMA.
// ---------------------------------------------------------------------------
__global__ __launch_bounds__(256) void qkv_gemm_mfma(
    const ushort_t* __restrict__ Xb, const ushort_t* __restrict__ Wt,
    const float* __restrict__ bq, const float* __restrict__ bk,
    const float* __restrict__ bv,
    ushort_t* __restrict__ Q, ushort_t* __restrict__ K, ushort_t* __restrict__ V)
{
    __shared__ __align__(16) ushort_t As[128 * 64];
    __shared__ __align__(16) ushort_t Bs[128 * 64];

    const int bx = blockIdx.x;          // 0..11
    const int m0 = blockIdx.y * 128;
    const int n0 = bx * 128;
    const int which = bx >> 2;          // 0=Q 1=K 2=V
    const bool isV = (which == 2);

    floatx4 acc[4][4];
#pragma unroll
    for (int i = 0; i < 4; ++i)
#pragma unroll
        for (int j = 0; j < 4; ++j) acc[i][j] = (floatx4)0.0f;

    if (isV) gemm128<TDIM, false>(Xb, Wt, m0, n0, As, Bs, acc);
    else     gemm128<TDIM, true >(Xb, Wt, m0, n0, As, Bs, acc);

    const int lane = threadIdx.x & 63;
    const int w    = threadIdx.x >> 6;
    const int l15  = lane & 15;
    const int quad = lane >> 4;
    const int wrow = w >> 1;
    const int wcol = w & 1;

    if (!isV) {
        const float* bias = (which == 0) ? bq : bk;
        const float scale = (which == 0) ? QSCALE : 1.0f;
        ushort_t* Out = (which == 0) ? Q : K;
#pragma unroll
        for (int mi = 0; mi < 4; ++mi) {
            const int m = m0 + wrow * 64 + mi * 16 + l15;
            const int b = m >> 11;
            const int s = m & 2047;
#pragma unroll
            for (int ni = 0; ni < 4; ++ni) {
                const int c = (n0 - which * HID) + wcol * 64 + ni * 16 + quad * 4;
                const int h = c >> 6;
                const int d0 = c & 63;
                const floatx4 b4 = *(const floatx4*)(bias + c);
                short4v pk;
#pragma unroll
                for (int r = 0; r < 4; ++r)
                    pk[r] = (short)bf16_rne((acc[mi][ni][r] + b4[r]) * scale);
                *(short4v*)&Out[((size_t)(b * NHEADS + h) * SEQ + s) * HDIM + d0] = pk;
            }
        }
    } else {
#pragma unroll
        for (int ni = 0; ni < 4; ++ni) {
            const int c = (n0 - 2 * HID) + wcol * 64 + ni * 16 + l15;
            const int h = c >> 6;
            const int d = c & 63;
            const float b1 = bv[c];
#pragma unroll
            for (int mi = 0; mi < 4; ++mi) {
                const int mb = m0 + wrow * 64 + mi * 16 + quad * 4;
                const int b = mb >> 11;
                const int s0 = mb & 2047;
                short4v pk;
#pragma unroll
                for (int r = 0; r < 4; ++r)
                    pk[r] = (short)bf16_rne(acc[mi][ni][r] + b1);
                *(short4v*)&V[((size_t)(b * NHEADS + h) * HDIM + d) * SEQ + s0] = pk;
            }
        }
    }
}

// ---------------------------------------------------------------------------
// Kernel 2: MFMA flash attention v5 (unchanged from R7 — best measured).
// ---------------------------------------------------------------------------
__global__ __launch_bounds__(512) void flash_attn_mfma(
    const ushort_t* __restrict__ Q, const ushort_t* __restrict__ K,
    const ushort_t* __restrict__ Vt, ushort_t* __restrict__ Opart,
    float* __restrict__ Lpart)
{
    __shared__ __align__(16) ushort_t lds[32768];   // 64 KB

    const int tid  = threadIdx.x;
    const int lane = tid & 63;
    const int w    = tid >> 6;     // 0..7
    const int l15  = lane & 15;
    const int quad = lane >> 4;
    const int key  = l15 & 7;

    const int bh = blockIdx.x;     // XCD locality
    const int b  = bh >> 3;
    const int h  = bh & 7;
    const int q0 = blockIdx.y * 256;
    const int z  = blockIdx.z;     // kk half
    const int kk0 = z * (SEQ / 2);

    const ushort_t* Qb = Q  + (size_t)bh * SEQ * HDIM;
    const ushort_t* Kb = K  + (size_t)bh * SEQ * HDIM + (size_t)kk0 * HDIM;
    const ushort_t* Vb = Vt + (size_t)bh * HDIM * SEQ + kk0;

    short8 qfA0, qfA1, qfB0, qfB1;
    {
        const ushort_t* qa = Qb + (size_t)(q0 + w * 32 + l15) * HDIM + quad * 8;
        qfA0 = *(const short8*)(qa);
        qfA1 = *(const short8*)(qa + 32);
        qfB0 = *(const short8*)(qa + 16 * HDIM);
        qfB1 = *(const short8*)(qa + 16 * HDIM + 32);
    }

    float lA = 0.f, lB = 0.f;
    floatx4 ofA[4], ofB[4];
#pragma unroll
    for (int t = 0; t < 4; ++t) { ofA[t] = (floatx4)0.0f; ofB[t] = (floatx4)0.0f; }

    const int srow = tid >> 3;        // 0..63
    const int sg   = tid & 7;
    const ushort_t* gK = Kb + (size_t)srow * HDIM + sg * 8;
    const ushort_t* gV = Vb + (size_t)srow * SEQ + sg * 8;
    const int sofs = srow * 64 + (sg ^ (srow & 7)) * 8;

    ushort_t* Pw = lds + 16384 + w * 2048;

    short8 kr = *(const short8*)(gK);
    short8 vr = *(const short8*)(gV);

    for (int it = 0; it < 16; ++it) {
        const int buf = it & 1;
        *(short8*)&lds[buf * 4096 + sofs]        = kr;
        *(short8*)&lds[8192 + buf * 4096 + sofs] = vr;
        __syncthreads();

        if (it < 15) {
            kr = *(const short8*)(gK + (size_t)(it + 1) * 64 * HDIM);
            vr = *(const short8*)(gV + (it + 1) * 64);
        }

        floatx4 saccA[4], saccB[4];
#pragma unroll
        for (int t = 0; t < 4; ++t) {
            const int kb = buf * 4096 + (t * 16 + l15) * 64;
            const short8 kf0 = *(const short8*)&lds[kb + (quad ^ key) * 8];
            const short8 kf1 = *(const short8*)&lds[kb + ((quad + 4) ^ key) * 8];
            floatx4 a = (floatx4)0.0f, bb = (floatx4)0.0f;
            a  = __builtin_amdgcn_mfma_f32_16x16x32_bf16(kf0, qfA0, a, 0, 0, 0);
            a  = __builtin_amdgcn_mfma_f32_16x16x32_bf16(kf1, qfA1, a, 0, 0, 0);
            bb = __builtin_amdgcn_mfma_f32_16x16x32_bf16(kf0, qfB0, bb, 0, 0, 0);
            bb = __builtin_amdgcn_mfma_f32_16x16x32_bf16(kf1, qfB1, bb, 0, 0, 0);
            saccA[t] = a;
            saccB[t] = bb;
        }

        float rsA = 0.f, rsB = 0.f;
#pragma unroll
        for (int t = 0; t < 4; ++t) {
            float pa[4], pb[4];
#pragma unroll
            for (int r = 0; r < 4; ++r) {
                pa[r] = exp2f(saccA[t][r]); rsA += pa[r];
                pb[r] = exp2f(saccB[t][r]); rsB += pb[r];
            }
            const int pofs = ((2 * t + (quad >> 1)) ^ key) * 8 + (quad & 1) * 4;
            {
                const unsigned u0 = __float_as_uint(pa[0]) + 0x8000u;
                const unsigned u1 = __float_as_uint(pa[1]) + 0x8000u;
                const unsigned u2 = __float_as_uint(pa[2]) + 0x8000u;
                const unsigned u3 = __float_as_uint(pa[3]) + 0x8000u;
                const unsigned lo = __builtin_amdgcn_perm(u1, u0, 0x07060302u);
                const unsigned hi = __builtin_amdgcn_perm(u3, u2, 0x07060302u);
                *(unsigned long long*)&Pw[l15 * 64 + pofs] =
                    ((unsigned long long)hi << 32) | lo;
            }
            {
                const unsigned u0 = __float_as_uint(pb[0]) + 0x8000u;
                const unsigned u1 = __float_as_uint(pb[1]) + 0x8000u;
                const unsigned u2 = __float_as_uint(pb[2]) + 0x8000u;
                const unsigned u3 = __float_as_uint(pb[3]) + 0x8000u;
                const unsigned lo = __builtin_amdgcn_perm(u1, u0, 0x07060302u);
                const unsigned hi = __builtin_amdgcn_perm(u3, u2, 0x07060302u);
                *(unsigned long long*)&Pw[(16 + l15) * 64 + pofs] =
                    ((unsigned long long)hi << 32) | lo;
            }
        }
        lA += rsA;
        lB += rsB;
        asm volatile("s_waitcnt lgkmcnt(0)" ::: "memory");

        const short8 pfA0 = *(const short8*)&Pw[l15 * 64 + (quad ^ key) * 8];
        const short8 pfA1 = *(const short8*)&Pw[l15 * 64 + ((quad + 4) ^ key) * 8];
        const short8 pfB0 = *(const short8*)&Pw[(16 + l15) * 64 + (quad ^ key) * 8];
        const short8 pfB1 = *(const short8*)&Pw[(16 + l15) * 64 + ((quad + 4) ^ key) * 8];

#pragma unroll
        for (int t = 0; t < 4; ++t) {
            const int vb2 = 8192 + buf * 4096 + (t * 16 + l15) * 64;
            const short8 vf0 = *(const short8*)&lds[vb2 + (quad ^ key) * 8];
            const short8 vf1 = *(const short8*)&lds[vb2 + ((quad + 4) ^ key) * 8];
            ofA[t] = __builtin_amdgcn_mfma_f32_16x16x32_bf16(vf0, pfA0, ofA[t], 0, 0, 0);
            ofA[t] = __builtin_amdgcn_mfma_f32_16x16x32_bf16(vf1, pfA1, ofA[t], 0, 0, 0);
            ofB[t] = __builtin_amdgcn_mfma_f32_16x16x32_bf16(vf0, pfB0, ofB[t], 0, 0, 0);
            ofB[t] = __builtin_amdgcn_mfma_f32_16x16x32_bf16(vf1, pfB1, ofB[t], 0, 0, 0);
        }
    }

    lA += __shfl_xor(lA, 16); lA += __shfl_xor(lA, 32);
    lB += __shfl_xor(lB, 16); lB += __shfl_xor(lB, 32);

    const int sA = q0 + w * 32 + l15;
    ushort_t* arowA = Opart + (size_t)z * MROWS * HID
                    + ((size_t)(b * SEQ + sA)) * HID + h * HDIM;
    ushort_t* arowB = arowA + (size_t)16 * HID;
#pragma unroll
    for (int t = 0; t < 4; ++t) {
        short4v pkA, pkB;
#pragma unroll
        for (int r = 0; r < 4; ++r) {
            pkA[r] = (short)bf16_rne(ofA[t][r]);
            pkB[r] = (short)bf16_rne(ofB[t][r]);
        }
        *(short4v*)&arowA[t * 16 + quad * 4] = pkA;
        *(short4v*)&arowB[t * 16 + quad * 4] = pkB;
    }
    if (quad == 0) {
        Lpart[(size_t)(z * 32 + bh) * SEQ + sA]      = lA;
        Lpart[(size_t)(z * 32 + bh) * SEQ + sA + 16] = lB;
    }
}

// ---------------------------------------------------------------------------
// Kernel 3: fused combine + output projection.
// Y[8192][768] = ((O0+O1)/(l0+l1)) * Wo + bo, all staged in-kernel.
// Tile 128m x 64n, 256 threads = 4 waves (wave w: rows w*32..+31).
// A staged via VGPR (combine + bf16 pack + XOR-swizzled ds_write);
// B (Wot [768][512]) via VGPR + swizzled ds_write.  K-loop: 8 iters of 64.
// XOR swizzle (16B granule, key=row&7) kills the 16-way frag-read conflicts.
// ---------------------------------------------------------------------------
__global__ __launch_bounds__(256) void out_proj_fused(
    const ushort_t* __restrict__ Opart, const float* __restrict__ Lpart,
    const ushort_t* __restrict__ Wot, const float* __restrict__ bo,
    float* __restrict__ Y)
{
    __shared__ __align__(16) ushort_t As[128 * 64];   // 16 KB
    __shared__ __align__(16) ushort_t Bs[64 * 64];    // 8 KB

    const int tid  = threadIdx.x;
    const int lane = tid & 63;
    const int w    = tid >> 6;
    const int l15  = lane & 15;
    const int quad = lane >> 4;
    const int key  = l15 & 7;

    const int n0 = blockIdx.x * 64;    // 0..11
    const int m0 = blockIdx.y * 128;   // 0..63

    // A staging map: row srow (2 threads/row), 4 granules each
    const int srow = tid >> 1;             // 0..127
    const int scol = (tid & 1) * 32;       // elem offset (granules 0..3 / 4..7)
    const int am   = m0 + srow;
    const int ab   = am >> 11;
    const int as   = am & 2047;
    const ushort_t* gO0 = Opart + (size_t)am * HID + scol;
    const ushort_t* gO1 = gO0 + (size_t)MROWS * HID;
    const int sk = srow & 7;

    // B staging map: rows tid>>3 and +32, granule tid&7
    const int brow = tid >> 3;             // 0..31
    const int bg   = tid & 7;
    const ushort_t* gB = Wot + (size_t)(n0 + brow) * HID + bg * 8;

    floatx4 acc[2][4];
#pragma unroll
    for (int i = 0; i < 2; ++i)
#pragma unroll
        for (int j = 0; j < 4; ++j) acc[i][j] = (floatx4)0.0f;

    for (int kt = 0; kt < HID; kt += 64) {
        const int h = kt >> 6;
        const int bh = ab * 8 + h;
        // ---- A: load O partials, combine, normalize, pack, swizzled write ----
        const float l = Lpart[(size_t)bh * SEQ + as] +
                        Lpart[(size_t)(32 + bh) * SEQ + as];
        const float inv = 1.f / l;
        if (kt) __syncthreads();
#pragma unroll
        for (int seg = 0; seg < 4; ++seg) {
            const short8 o0 = *(const short8*)(gO0 + h * 64 + seg * 8);
            const short8 o1 = *(const short8*)(gO1 + h * 64 + seg * 8);
            uint4v v;
#pragma unroll
            for (int p = 0; p < 4; ++p) {
                const float f0 = (bf16_to_f((ushort_t)o0[2 * p]) +
                                  bf16_to_f((ushort_t)o1[2 * p])) * inv;
                const float f1 = (bf16_to_f((ushort_t)o0[2 * p + 1]) +
                                  bf16_to_f((ushort_t)o1[2 * p + 1])) * inv;
                const unsigned u0 = __float_as_uint(f0) + 0x8000u;
                const unsigned u1 = __float_as_uint(f1) + 0x8000u;
                v[p] = __builtin_amdgcn_perm(u1, u0, 0x07060302u);
            }
            const int g = (scol >> 3) + seg;          // logical granule 0..7
            *(uint4v*)&As[srow * 64 + (g ^ sk) * 8] = v;
        }
        // ---- B: two swizzled granules ----
        {
            const short8 b0 = *(const short8*)(gB + kt);
            const short8 b1 = *(const short8*)(gB + (size_t)32 * HID + kt);
            *(short8*)&Bs[brow * 64 + (bg ^ (brow & 7)) * 8] = b0;
            *(short8*)&Bs[(brow + 32) * 64 + (bg ^ (brow & 7)) * 8] = b1;
        }
        __syncthreads();

        // ---- MFMA: acc[t][n] (swapped orientation: m on l15, n on regs) ----
#pragma unroll
        for (int half = 0; half < 2; ++half) {
            short8 af[2], bf[4];
#pragma unroll
            for (int t = 0; t < 2; ++t) {
                const int row = w * 32 + t * 16 + l15;
                af[t] = *(const short8*)&As[row * 64 + (((half * 4) + quad) ^ key) * 8];
            }
#pragma unroll
            for (int n = 0; n < 4; ++n) {
                const int row = n * 16 + l15;
                bf[n] = *(const short8*)&Bs[row * 64 + (((half * 4) + quad) ^ key) * 8];
            }
#pragma unroll
            for (int t = 0; t < 2; ++t)
#pragma unroll
                for (int n = 0; n < 4; ++n)
                    acc[t][n] = __builtin_amdgcn_mfma_f32_16x16x32_bf16(
                        bf[n], af[t], acc[t][n], 0, 0, 0);
        }
    }

    // ---- epilogue: bias + coalesced float4 stores ----
#pragma unroll
    for (int t = 0; t < 2; ++t) {
        const int m = m0 + w * 32 + t * 16 + l15;
#pragma unroll
        for (int n = 0; n < 4; ++n) {
            const int nb = n0 + n * 16 + quad * 4;
            const floatx4 b4 = *(const floatx4*)(bo + nb);
            floatx4 o;
#pragma unroll
            for (int r = 0; r < 4; ++r) o[r] = acc[t][n][r] + b4[r];
            *(floatx4*)&Y[(size_t)m * VDIM + nb] = o;
        }
    }
}

// ---------------------------------------------------------------------------
extern "C" void kernel_launch(void* const* d_in, const int* in_sizes, int n_in,
                              void* d_out, int out_size, void* d_ws, size_t ws_size,
                              hipStream_t stream)
{
    const float* text = (const float*)d_in[0];
    const float* Wq = (const float*)d_in[1];
    const float* bq = (const float*)d_in[2];
    const float* Wk = (const float*)d_in[3];
    const float* bk = (const float*)d_in[4];
    const float* Wv = (const float*)d_in[5];
    const float* bv = (const float*)d_in[6];
    const float* Wo = (const float*)d_in[7];
    const float* bo = (const float*)d_in[8];
    float* out = (float*)d_out;

    // ws layout (ushorts): Xb | Wqkvt | Wot | Q | K | Vt | Opart(2x) | Lpart
    ushort_t* Xb    = (ushort_t*)d_ws;
    ushort_t* Wqkvt = Xb + (size_t)MROWS * TDIM;
    ushort_t* Wot   = Wqkvt + (size_t)NQKV * TDIM;
    ushort_t* Qw    = Wot + (size_t)VDIM * HID;
    ushort_t* Kw    = Qw + (size_t)MROWS * HID;
    ushort_t* Vtw   = Kw + (size_t)MROWS * HID;
    ushort_t* Opart = Vtw + (size_t)MROWS * HID;
    float*    Lpart = (float*)(Opart + (size_t)2 * MROWS * HID);

    prep<<<dim3(8448), 256, 0, stream>>>(text, Xb, Wq, Wk, Wv, Wo, Wqkvt, Wot);
    qkv_gemm_mfma<<<dim3(12, 64), 256, 0, stream>>>(Xb, Wqkvt, bq, bk, bv, Qw, Kw, Vtw);
    flash_attn_mfma<<<dim3(32, 8, 2), 512, 0, stream>>>(Qw, Kw, Vtw, Opart, Lpart);
    out_proj_fused<<<dim3(12, 64), 256, 0, stream>>>(Opart, Lpart, Wot, bo, out);
}